// Round 7
// baseline (1292.102 us; speedup 1.0000x reference)
//
#include <hip/hip_runtime.h>

typedef _Float16 half_t;
typedef _Float16 half8 __attribute__((ext_vector_type(8)));
typedef float floatx4 __attribute__((ext_vector_type(4)));

#define NSEQ   256      // B*S
#define TLEN   128
#define EMBD   512
#define UNITSZ 512
#define GC     2048     // 4*UNITS
#define NTOK   32768    // NSEQ*TLEN
#define NCOL   4096     // 2 dirs * GC
#define KDIM   512

// workspace layout (bytes)
constexpr size_t OFF_EMB = 0;                    // emb_f16: NTOK*512*2 = 33,554,432
constexpr size_t OFF_WT  = 33554432;             // WcatT fp16 [4096][512] = 4,194,304
constexpr size_t OFF_UT  = OFF_WT + 4194304;     // UcatT fp16 [4096][512] = 4,194,304
constexpr size_t OFF_HB  = OFF_UT + 4194304;     // hbuf fp16 [64 chains][2 par][8 rows][512] = 1,048,576
constexpr size_t OFF_CNT = OFF_HB + 1048576;     // seq slots: 64 chains * 16 u32 = 4096 B
constexpr size_t OFF_MSK = OFF_CNT + 4096;       // mask bits: 256 * 2 u64 = 4096 B
constexpr size_t OFF_XW  = OFF_MSK + 4096;       // xW fp16 [32768][4096] = 268,435,456

__device__ inline float sigm(float x)  { return 1.0f / (1.0f + __expf(-x)); }
__device__ inline float tanhx(float x) { return 2.0f / (1.0f + __expf(-2.0f * x)) - 1.0f; }

// coherent (agent-scope, bypass non-coherent L1/L2) loads/stores
__device__ inline unsigned long long ld8c(const void* p) {
    return __hip_atomic_load((const unsigned long long*)p, __ATOMIC_RELAXED, __HIP_MEMORY_SCOPE_AGENT);
}
__device__ inline void st8c(void* p, unsigned long long v) {
    __hip_atomic_store((unsigned long long*)p, v, __ATOMIC_RELAXED, __HIP_MEMORY_SCOPE_AGENT);
}
__device__ inline unsigned ld4c(const void* p) {
    return __hip_atomic_load((const unsigned*)p, __ATOMIC_RELAXED, __HIP_MEMORY_SCOPE_AGENT);
}
__device__ inline void st4c(void* p, unsigned v) {
    __hip_atomic_store((unsigned*)p, v, __ATOMIC_RELAXED, __HIP_MEMORY_SCOPE_AGENT);
}

// ---------------- pack W/U (fp32 [512][2048] per dir) -> transposed fp16 [dir*2048+gcol][512]
__global__ void pack_kernel(const float* __restrict__ Wf, const float* __restrict__ Uf,
                            const float* __restrict__ Wb, const float* __restrict__ Ub,
                            half_t* __restrict__ WT, half_t* __restrict__ UT) {
    int c = blockIdx.x * 256 + threadIdx.x;
    int arr = c >> 18;
    int r = c & 262143;
    int kc = r >> 12;
    int gc = r & 4095;
    int dir = gc >> 11;
    int g = gc & 2047;
    const float* src = (arr == 0) ? (dir ? Wb : Wf) : (dir ? Ub : Uf);
    half_t* dst = (arr == 0) ? WT : UT;
    half8 v;
#pragma unroll
    for (int j = 0; j < 8; ++j)
        v[j] = (half_t)src[(size_t)(kc * 8 + j) * GC + g];
    *(half8*)(dst + (size_t)gc * KDIM + kc * 8) = v;
}

// ---------------- zero hbuf + seq slots
__global__ void zero_kernel(unsigned* __restrict__ hb_and_cnt) {
    int i = blockIdx.x * 256 + threadIdx.x;          // 263168 dwords = hbuf(1MB)+cnt(4KB)
    if (i < 263168) hb_and_cnt[i] = 0u;
}

// ---------------- pack per-row validity masks: mk[n] = 128 bits of (x!=0)
__global__ void mask_kernel(const int* __restrict__ x, unsigned long long* __restrict__ mk) {
    int n = blockIdx.x;
    int l = threadIdx.x;
    unsigned long long b0 = __ballot(x[n * TLEN + l] != 0);
    unsigned long long b1 = __ballot(x[n * TLEN + 64 + l] != 0);
    if (l == 0) { mk[n * 2] = b0; mk[n * 2 + 1] = b1; }
}

// ---------------- gather: emb_f16[token][512] = fp16(emb_table[x[token]][:])
__global__ void gather_kernel(const int* __restrict__ x, const float* __restrict__ tab,
                              half_t* __restrict__ embf) {
    int g = blockIdx.x * 256 + threadIdx.x;
    int token = g >> 6;
    int k = (g & 63) * 8;
    int id = x[token];
    const float* s = tab + (size_t)id * EMBD + k;
    float4 a = *(const float4*)(s);
    float4 b = *(const float4*)(s + 4);
    half8 v;
    v[0] = (half_t)a.x; v[1] = (half_t)a.y; v[2] = (half_t)a.z; v[3] = (half_t)a.w;
    v[4] = (half_t)b.x; v[5] = (half_t)b.y; v[6] = (half_t)b.z; v[7] = (half_t)b.w;
    *(half8*)(embf + (size_t)token * EMBD + k) = v;
}

// ---------------- GEMM: xW[32768][4096] = emb_f16 @ WcatT^T + bias, fp16 out
__global__ __launch_bounds__(256, 2) void gemm_kernel(const half_t* __restrict__ embf,
                                                      const half_t* __restrict__ WT,
                                                      const float* __restrict__ bf,
                                                      const float* __restrict__ bb,
                                                      half_t* __restrict__ xw) {
    __shared__ half_t As[128 * 40];
    __shared__ half_t Bs[128 * 40];
    int bx = blockIdx.x;
    int bm = bx & 255, bn = bx >> 8;
    int r0 = bm * 128, c0 = bn * 128;
    int tid = threadIdx.x;
    int w = tid >> 6, l = tid & 63;
    int q = l >> 4, cl = l & 15;
    int mq = (w >> 1) * 64, nq = (w & 1) * 64;

    floatx4 acc[4][4];
#pragma unroll
    for (int a = 0; a < 4; ++a)
#pragma unroll
        for (int b = 0; b < 4; ++b) acc[a][b] = (floatx4){0.f, 0.f, 0.f, 0.f};

    for (int kb = 0; kb < 16; ++kb) {
#pragma unroll
        for (int cc = 0; cc < 2; ++cc) {
            int c = tid + cc * 256;
            int row = c >> 2, qt = c & 3;
            half8 va = *(const half8*)(embf + (size_t)(r0 + row) * KDIM + kb * 32 + qt * 8);
            *(half8*)(As + row * 40 + qt * 8) = va;
            half8 vb = *(const half8*)(WT + (size_t)(c0 + row) * KDIM + kb * 32 + qt * 8);
            *(half8*)(Bs + row * 40 + qt * 8) = vb;
        }
        __syncthreads();
        half8 af[4], bfr[4];
#pragma unroll
        for (int mb = 0; mb < 4; ++mb)
            af[mb] = *(const half8*)(As + (mq + mb * 16 + cl) * 40 + q * 8);
#pragma unroll
        for (int nb = 0; nb < 4; ++nb)
            bfr[nb] = *(const half8*)(Bs + (nq + nb * 16 + cl) * 40 + q * 8);
#pragma unroll
        for (int mb = 0; mb < 4; ++mb)
#pragma unroll
            for (int nb = 0; nb < 4; ++nb)
                acc[mb][nb] = __builtin_amdgcn_mfma_f32_16x16x32_f16(af[mb], bfr[nb], acc[mb][nb], 0, 0, 0);
        __syncthreads();
    }
#pragma unroll
    for (int nb = 0; nb < 4; ++nb) {
        int col = c0 + nq + nb * 16 + cl;
        int dir = col >> 11, gcol = col & 2047;
        float bias = dir ? bb[gcol] : bf[gcol];
#pragma unroll
        for (int mb = 0; mb < 4; ++mb) {
#pragma unroll
            for (int r = 0; r < 4; ++r) {
                int row = r0 + mq + mb * 16 + q * 4 + r;
                xw[(size_t)row * NCOL + col] = (half_t)(acc[mb][nb][r] + bias);
            }
        }
    }
}

// ---------------- persistent bidirectional LSTM, 2-chain interleaved.
// 64 chains (2 dir x 32 rowg of 8 rows). Each WG serves chains (dir,p) and
// (dir,p+16) with the SAME register-resident U slice, alternating phases.
// While chain A's h-exchange round-trip (store->LLC->peer poll->stage) is in
// flight, the WG computes chain B's step -- hiding the exchange latency that
// R3-R6 showed is the structural floor (~5.7us/step flat across 3 reorderings).
// Signals: per-WG plain coherent stores to distinct slots (no same-address
// RMW); poll: one per-lane load + ballot over the chain's 8 slots.
__global__ __launch_bounds__(256, 1) void lstm_kernel(const half_t* __restrict__ xw,
                                                      const half_t* __restrict__ UT,
                                                      half_t* __restrict__ hbuf,
                                                      const unsigned long long* __restrict__ mk,
                                                      float* __restrict__ out,
                                                      unsigned* __restrict__ cnt) {
    __shared__ half_t Ast[8192];   // 16 kk * 64 ll * 8 halves (rows 8-15 pre-zeroed)
    __shared__ half_t Pk[512];     // 8 rows x 64 units
    int bx = blockIdx.x;
    int dir = bx >> 7;
    int p = (bx >> 3) & 15;        // pair id
    int wgc = bx & 7;
    int tid = threadIdx.x;
    int w = tid >> 6, l = tid & 63;
    int q = l >> 4, cl = l & 15;
    int cg = wgc * 4 + w;
    int ub = cg * 16;              // unit base (per wave)
    int ub0 = wgc * 64;            // unit base (per WG)
    bool val = (q < 2);            // lanes owning valid acc rows 0-7
    int rowg[2] = {p, p + 16};

    // preload U B-frags (shared by both chains: same dir, same cols)
    half8 bfrag[64];
#pragma unroll
    for (int kk = 0; kk < 16; ++kk)
#pragma unroll
        for (int cf = 0; cf < 4; ++cf)
            bfrag[kk * 4 + cf] = *(const half8*)(UT + (size_t)(dir * 2048 + cf * 512 + ub + cl) * KDIM + kk * 32 + q * 8);

    // validity masks for both chains (q>=2 lanes load harmless duplicates)
    unsigned long long mlo[2][4], mhi[2][4];
#pragma unroll
    for (int ph = 0; ph < 2; ++ph)
#pragma unroll
        for (int r = 0; r < 4; ++r) {
            int n = rowg[ph] * 8 + (q & 1) * 4 + r;
            mlo[ph][r] = mk[n * 2];
            mhi[ph][r] = mk[n * 2 + 1];
        }

    float cs[2][4] = {{0.f,0.f,0.f,0.f},{0.f,0.f,0.f,0.f}};
    float hs[2][4] = {{0.f,0.f,0.f,0.f},{0.f,0.f,0.f,0.f}};
    int colb = dir * 2048 + ub + cl;

    // xv[ph][g*4+r]: prefetched xW for that chain's upcoming step
    half_t xv[2][16];
    if (val) {
        int tI = dir ? 127 : 0;
#pragma unroll
        for (int r = 0; r < 4; ++r) {
            size_t ro = ((size_t)(rowg[0] * 8 + q * 4 + r) * TLEN + tI) * NCOL;
#pragma unroll
            for (int g = 0; g < 4; ++g)
                xv[0][g * 4 + r] = xw[ro + colb + g * 512];
        }
    }

    // pre-zero Ast rows 8-15 (A-operand rows for lanes cl>=8) ONCE
#pragma unroll
    for (int cc = 0; cc < 2; ++cc) {
        int c = tid + cc * 256;          // 512 chunks
        int kk = c >> 5, j = c & 31;
        int qd = j >> 3, mm = 8 + (j & 7);
        half8 z = {(half_t)0,(half_t)0,(half_t)0,(half_t)0,(half_t)0,(half_t)0,(half_t)0,(half_t)0};
        *(half8*)(Ast + (kk * 64 + qd * 16 + mm) * 8) = z;
    }
    __syncthreads();

#pragma unroll 1
    for (int t = 0; t < TLEN; ++t) {
#pragma unroll
        for (int ph = 0; ph < 2; ++ph) {
            int rg = rowg[ph];
            int chain = dir * 32 + rg;
            unsigned* sq = cnt + chain * 16;
            // wait for all 8 peers of this chain to have published step t
            if (w == 0) {
                for (;;) {
                    unsigned v = ld4c(sq + (l & 7));
                    if (!__ballot(v < (unsigned)t)) break;
                    __builtin_amdgcn_s_sleep(1);
                }
            }
            __syncthreads();
            // stage this chain's 8 h-rows into Ast rows 0-7 (frag order)
            const half_t* hsrc = hbuf + (((size_t)chain * 2 + (t & 1)) * 8) * UNITSZ;
#pragma unroll
            for (int cc = 0; cc < 2; ++cc) {
                int c = tid + cc * 256;        // 512 chunks of 16B
                int kk = c >> 5, j = c & 31;
                int qd = j >> 3, m = j & 7;
                int koff = kk * 32 + qd * 8;
                const half_t* sp = hsrc + (size_t)m * UNITSZ + koff;
                union { unsigned long long u[2]; half8 v; } cv;
                cv.u[0] = ld8c(sp);
                cv.u[1] = ld8c(sp + 4);
                *(half8*)(Ast + (kk * 64 + qd * 16 + m) * 8) = cv.v;
            }
            __syncthreads();
            // acc init from prefetched xW (invalid lanes: 0)
            floatx4 a0, a1, a2, a3;
#pragma unroll
            for (int r = 0; r < 4; ++r) {
                a0[r] = val ? (float)xv[ph][0 * 4 + r] : 0.f;
                a1[r] = val ? (float)xv[ph][1 * 4 + r] : 0.f;
                a2[r] = val ? (float)xv[ph][2 * 4 + r] : 0.f;
                a3[r] = val ? (float)xv[ph][3 * 4 + r] : 0.f;
            }
            // z += h @ U
#pragma unroll
            for (int kk = 0; kk < 16; ++kk) {
                half8 af = *(const half8*)(Ast + (kk * 64 + l) * 8);
                a0 = __builtin_amdgcn_mfma_f32_16x16x32_f16(af, bfrag[kk * 4 + 0], a0, 0, 0, 0);
                a1 = __builtin_amdgcn_mfma_f32_16x16x32_f16(af, bfrag[kk * 4 + 1], a1, 0, 0, 0);
                a2 = __builtin_amdgcn_mfma_f32_16x16x32_f16(af, bfrag[kk * 4 + 2], a2, 0, 0, 0);
                a3 = __builtin_amdgcn_mfma_f32_16x16x32_f16(af, bfrag[kk * 4 + 3], a3, 0, 0, 0);
            }
            // gates + masked state update; repack h into Pk (valid lanes only)
            int tIdx = dir ? (127 - t) : t;
            if (val) {
#pragma unroll
                for (int r = 0; r < 4; ++r) {
                    unsigned long long mw = (tIdx & 64) ? mhi[ph][r] : mlo[ph][r];
                    bool keep = (mw >> (tIdx & 63)) & 1ull;
                    float iv = sigm(a0[r]);
                    float fv = sigm(a1[r]);
                    float gv = tanhx(a2[r]);
                    float ov = sigm(a3[r]);
                    float cn = fv * cs[ph][r] + iv * gv;
                    float hn = ov * tanhx(cn);
                    if (keep) { cs[ph][r] = cn; hs[ph][r] = hn; }
                    Pk[(q * 4 + r) * 64 + w * 16 + cl] = (half_t)hs[ph][r];
                }
            }
            __syncthreads();
            // (1) pack store, wave 0 only (so one wave's vmcnt covers all stores)
            half_t* hdst = hbuf + (((size_t)chain * 2 + ((t + 1) & 1)) * 8) * UNITSZ;
            if (w == 0) {
                int prow = l >> 3, pu = (l & 7) * 8;
                const unsigned long long* ps = (const unsigned long long*)(Pk + prow * 64 + pu);
                st8c(hdst + (size_t)prow * UNITSZ + ub0 + pu, ps[0]);
                st8c(hdst + (size_t)prow * UNITSZ + ub0 + pu + 4, ps[1]);
            }
            asm volatile("" ::: "memory");   // keep stores older than prefetch
            // (2) prefetch NEXT phase's xW (other chain): stays in flight across signal
            int nph = ph ^ 1;
            int ntv = (ph == 0) ? t : t + 1;
            if (ntv < TLEN && val) {
                int tN = dir ? (127 - ntv) : ntv;
                int nrg = rowg[nph];
#pragma unroll
                for (int r = 0; r < 4; ++r) {
                    size_t ro = ((size_t)(nrg * 8 + q * 4 + r) * TLEN + tN) * NCOL;
#pragma unroll
                    for (int g = 0; g < 4; ++g)
                        xv[nph][g * 4 + r] = xw[ro + colb + g * 512];
                }
            }
            // (3) wait for the 2 pack stores only (16 prefetch loads stay flying)
            asm volatile("s_waitcnt vmcnt(16)" ::: "memory");
            // (4) publish step t+1 to this WG's slot (plain coherent store, no RMW)
            if (tid == 0) st4c(sq + wgc, (unsigned)(t + 1));
        }
    }
    // final output
    if (val) {
#pragma unroll
        for (int ph = 0; ph < 2; ++ph)
#pragma unroll
            for (int r = 0; r < 4; ++r) {
                int n = rowg[ph] * 8 + q * 4 + r;
                out[(size_t)n * 1024 + dir * 512 + ub + cl] = hs[ph][r];
            }
    }
}

extern "C" void kernel_launch(void* const* d_in, const int* in_sizes, int n_in,
                              void* d_out, int out_size, void* d_ws, size_t ws_size,
                              hipStream_t stream) {
    const int*   x    = (const int*)d_in[0];
    const float* tab  = (const float*)d_in[1];
    const float* Wf   = (const float*)d_in[2];
    const float* Uf   = (const float*)d_in[3];
    const float* bf   = (const float*)d_in[4];
    const float* Wb   = (const float*)d_in[5];
    const float* Ub   = (const float*)d_in[6];
    const float* bb   = (const float*)d_in[7];
    float* out = (float*)d_out;

    char* ws = (char*)d_ws;
    half_t*   embf = (half_t*)(ws + OFF_EMB);
    half_t*   WT   = (half_t*)(ws + OFF_WT);
    half_t*   UT   = (half_t*)(ws + OFF_UT);
    half_t*   hbuf = (half_t*)(ws + OFF_HB);
    unsigned* cnt  = (unsigned*)(ws + OFF_CNT);
    unsigned long long* mkb = (unsigned long long*)(ws + OFF_MSK);
    half_t*   xw   = (half_t*)(ws + OFF_XW);
    unsigned* hbz  = (unsigned*)(ws + OFF_HB);   // zero range covers hbuf + cnt (contiguous)

    pack_kernel<<<2048, 256, 0, stream>>>(Wf, Uf, Wb, Ub, WT, UT);
    zero_kernel<<<1028, 256, 0, stream>>>(hbz);
    mask_kernel<<<256, 64, 0, stream>>>(x, mkb);
    gather_kernel<<<8192, 256, 0, stream>>>(x, tab, embf);
    gemm_kernel<<<8192, 256, 0, stream>>>(embf, WT, bf, bb, xw);
    lstm_kernel<<<256, 256, 0, stream>>>(xw, UT, hbuf, mkb, out, cnt);
}